// Round 6
// baseline (33.174 us; speedup 1.0000x reference)
//
#include <hip/hip_runtime.h>
#include <hip/hip_bf16.h>

#define BB 2
#define SS 128
#define HH 1024
#define AA 256
#define CC 14
#define R_TOT (BB*SS)   // 256 rows per net

struct NetP { const float *W1,*b1,*W2,*b2,*s0W,*s0b,*s1W,*s1b; };
struct AllP { NetP n[3]; };

// ws float offsets
#define S0_OFF 0                         // [3][256][14]
#define S1_OFF (3*R_TOT*CC)
// bf16 weight copies (ushort), placed past the fp32 region (byte offsets)
#define W1B_OFF_BYTES (64*1024)                      // 3*1024*256 ushort = 1.5 MB
#define W2B_OFF_BYTES (W1B_OFF_BYTES + 3*HH*AA*2)    // 3*256*256 ushort = 384 KB

#define W1_ELEMS (3*HH*AA)   // 786432
#define W2_ELEMS (3*AA*AA)   // 196608

__device__ __forceinline__ float bf16u_to_f(unsigned short u) {
    return __uint_as_float(((unsigned)u) << 16);
}

// ---------------------------------------------------------------------------
// K0: convert W1, W2 (fp32) -> bf16 (RNE) into ws. 480 blocks x 512 thr x 4.
// ---------------------------------------------------------------------------
__global__ __launch_bounds__(512)
void cvt_kernel(AllP P, unsigned short* __restrict__ w1b,
                unsigned short* __restrict__ w2b)
{
    const int idx0 = (blockIdx.x * 512 + threadIdx.x) * 4;
    #pragma unroll
    for (int u = 0; u < 4; ++u) {
        const int idx = idx0 + u;
        if (idx < W1_ELEMS) {
            const int net = idx / (HH*AA), r = idx % (HH*AA);
            const float v = P.n[net].W1[r];
            w1b[idx] = __bfloat16_as_ushort(__float2bfloat16(v));
        } else if (idx < W1_ELEMS + W2_ELEMS) {
            const int j = idx - W1_ELEMS;
            const int net = j / (AA*AA), r = j % (AA*AA);
            const float v = P.n[net].W2[r];
            w2b[j] = __bfloat16_as_ushort(__float2bfloat16(v));
        }
    }
}

// ---------------------------------------------------------------------------
// K_A: fully fused MLP per 4-row tile, bf16 weights (fp32 accumulate).
// grid = net(3) * rowtile(64 of 4 rows) = 192 blocks, 512 thr = 8 waves.
// Layer 1: wave w owns K-chunk [w*128,w*128+128); lane owns 4 cols (ushort4).
// Layer 2: wave w owns K-chunk [w*32, w*32+32).
// ---------------------------------------------------------------------------
__global__ __launch_bounds__(512)
void mlp_fused(const float* __restrict__ mem, AllP P,
               const unsigned short* __restrict__ w1b,
               const unsigned short* __restrict__ w2b,
               float* __restrict__ s0o, float* __restrict__ s1o)
{
    const int bx   = blockIdx.x;
    const int net  = bx >> 6;           // 0..2
    const int rt   = bx & 63;           // 0..63
    const int row0 = rt * 4;
    const NetP p  = P.n[net];
    const int tid  = threadIdx.x;
    const int lane = tid & 63;
    const int wv   = __builtin_amdgcn_readfirstlane(tid >> 6); // 0..7
    const int col4 = 4 * lane;          // column base (4 cols/lane)

    __shared__ float part[8][4][AA];    // 32 KB
    __shared__ float hidL[4][AA];       // 4 KB
    __shared__ float outL[4][AA];       // 4 KB
    __shared__ float pp[112][4];        // 1.75 KB

    // ================= layer 1 =================
    {
        const int k0 = wv * 128;
        const unsigned short* __restrict__ W1p =
            w1b + (size_t)net*HH*AA + (size_t)k0*AA + col4;
        const float* __restrict__ m0 = mem + (size_t)(row0+0)*HH + k0;
        const float* __restrict__ m1 = mem + (size_t)(row0+1)*HH + k0;
        const float* __restrict__ m2 = mem + (size_t)(row0+2)*HH + k0;
        const float* __restrict__ m3 = mem + (size_t)(row0+3)*HH + k0;
        float4 a0 = {0,0,0,0}, a1 = {0,0,0,0}, a2 = {0,0,0,0}, a3 = {0,0,0,0};
        #pragma unroll 8
        for (int kk = 0; kk < 128; ++kk) {
            const ushort4 wu = *(const ushort4*)(W1p + (size_t)kk*AA);
            const float wx = bf16u_to_f(wu.x), wy = bf16u_to_f(wu.y);
            const float wz = bf16u_to_f(wu.z), ww = bf16u_to_f(wu.w);
            const float v0 = m0[kk], v1 = m1[kk], v2 = m2[kk], v3 = m3[kk]; // uniform -> s_load
            a0.x = fmaf(v0, wx, a0.x); a0.y = fmaf(v0, wy, a0.y);
            a0.z = fmaf(v0, wz, a0.z); a0.w = fmaf(v0, ww, a0.w);
            a1.x = fmaf(v1, wx, a1.x); a1.y = fmaf(v1, wy, a1.y);
            a1.z = fmaf(v1, wz, a1.z); a1.w = fmaf(v1, ww, a1.w);
            a2.x = fmaf(v2, wx, a2.x); a2.y = fmaf(v2, wy, a2.y);
            a2.z = fmaf(v2, wz, a2.z); a2.w = fmaf(v2, ww, a2.w);
            a3.x = fmaf(v3, wx, a3.x); a3.y = fmaf(v3, wy, a3.y);
            a3.z = fmaf(v3, wz, a3.z); a3.w = fmaf(v3, ww, a3.w);
        }
        *(float4*)&part[wv][0][col4] = a0;
        *(float4*)&part[wv][1][col4] = a1;
        *(float4*)&part[wv][2][col4] = a2;
        *(float4*)&part[wv][3][col4] = a3;
    }
    __syncthreads();
    for (int i = tid; i < 4*AA; i += 512) {
        const int r = i >> 8, u = i & (AA-1);
        float s = p.b1[u];
        #pragma unroll
        for (int w = 0; w < 8; ++w) s += part[w][r][u];
        hidL[r][u] = fmaxf(s, 0.f);
    }
    __syncthreads();

    // ================= layer 2 =================
    {
        const int k0 = wv * 32;
        const unsigned short* __restrict__ W2p =
            w2b + (size_t)net*AA*AA + (size_t)k0*AA + col4;
        float4 a0 = {0,0,0,0}, a1 = {0,0,0,0}, a2 = {0,0,0,0}, a3 = {0,0,0,0};
        #pragma unroll 8
        for (int kk = 0; kk < 32; ++kk) {
            const ushort4 wu = *(const ushort4*)(W2p + (size_t)kk*AA);
            const float wx = bf16u_to_f(wu.x), wy = bf16u_to_f(wu.y);
            const float wz = bf16u_to_f(wu.z), ww = bf16u_to_f(wu.w);
            const float v0 = hidL[0][k0+kk], v1 = hidL[1][k0+kk];  // LDS broadcast
            const float v2 = hidL[2][k0+kk], v3 = hidL[3][k0+kk];
            a0.x = fmaf(v0, wx, a0.x); a0.y = fmaf(v0, wy, a0.y);
            a0.z = fmaf(v0, wz, a0.z); a0.w = fmaf(v0, ww, a0.w);
            a1.x = fmaf(v1, wx, a1.x); a1.y = fmaf(v1, wy, a1.y);
            a1.z = fmaf(v1, wz, a1.z); a1.w = fmaf(v1, ww, a1.w);
            a2.x = fmaf(v2, wx, a2.x); a2.y = fmaf(v2, wy, a2.y);
            a2.z = fmaf(v2, wz, a2.z); a2.w = fmaf(v2, ww, a2.w);
            a3.x = fmaf(v3, wx, a3.x); a3.y = fmaf(v3, wy, a3.y);
            a3.z = fmaf(v3, wz, a3.z); a3.w = fmaf(v3, ww, a3.w);
        }
        __syncthreads();   // all layer-1 part reads done before overwrite
        *(float4*)&part[wv][0][col4] = a0;
        *(float4*)&part[wv][1][col4] = a1;
        *(float4*)&part[wv][2][col4] = a2;
        *(float4*)&part[wv][3][col4] = a3;
    }
    __syncthreads();
    for (int i = tid; i < 4*AA; i += 512) {
        const int r = i >> 8, u = i & (AA-1);
        float s = p.b2[u];
        #pragma unroll
        for (int w = 0; w < 8; ++w) s += part[w][r][u];
        outL[r][u] = s;
    }
    __syncthreads();

    // ================= projections to C=14 =================
    if (tid < 448) {
        const int task = tid >> 2, kc = tid & 3;
        const int which = (task >= 56) ? 1 : 0;
        const int rem2  = task - which*56;
        const int rr = rem2 / CC, c = rem2 % CC;
        const float* __restrict__ W = which ? p.s1W : p.s0W;
        float s = 0.f;
        #pragma unroll 4
        for (int k = kc*64; k < kc*64 + 64; ++k)
            s = fmaf(outL[rr][k], W[(size_t)k*CC + c], s);
        pp[task][kc] = s;
    }
    __syncthreads();
    if (tid < 112) {
        const int which = (tid >= 56) ? 1 : 0;
        const int rem2  = tid - which*56;
        const int rr = rem2 / CC, c = rem2 % CC;
        const float s = pp[tid][0]+pp[tid][1]+pp[tid][2]+pp[tid][3]
                      + (which ? p.s1b : p.s0b)[c];
        (which ? s1o : s0o)[((size_t)net*R_TOT + row0 + rr)*CC + c] = s;
    }
}

// ---------------------------------------------------------------------------
// K_B: fused prefix + output fill (unchanged — proven).
// ---------------------------------------------------------------------------
__global__ __launch_bounds__(512)
void final_kernel(const float* __restrict__ s0w, const float* __restrict__ s1w,
                  const float* __restrict__ uni, float* __restrict__ out)
{
    const int bi = blockIdx.x;        // b*S + i
    const int b = bi >> 7, i = bi & (SS-1);
    const int tid = threadIdx.x;
    const int lane = tid & 63;
    const int k    = tid & 127;       // scan position
    const int wv2  = (tid >> 6) & 1;  // half within scan pair
    const int slot = tid >> 7;        // 0..3: which c this pass

    __shared__ float E[SS*CC];        // 7 KB
    __shared__ float Qe[SS*CC];       // 7 KB
    __shared__ float red[4][4][2];
    __shared__ float mnL[CC], sh1L[CC], uniL[CC];

    if (tid < CC) {
        sh1L[tid] = s1w[(size_t)bi*CC + tid];
        uniL[tid] = uni[tid];
    }

    const float* __restrict__ sm0b = s0w + (size_t)(2*R_TOT + b*SS)*CC;
    const float* __restrict__ sm1b = s1w + (size_t)(2*R_TOT + b*SS)*CC;

    for (int pass = 0; pass < 4; ++pass) {
        const int c = pass*4 + slot;
        float x0 = 0.f, x1 = 0.f, e = 0.f, q = 0.f;
        if (c < CC) {
            x0 = sm0b[(size_t)k*CC + c];
            x1 = sm1b[(size_t)k*CC + c];
            float m = x0;
            #pragma unroll
            for (int off = 32; off >= 1; off >>= 1) m = fmaxf(m, __shfl_xor(m, off));
            float ss = x1;
            #pragma unroll
            for (int off = 32; off >= 1; off >>= 1) ss += __shfl_xor(ss, off);
            if (lane == 0) { red[0][slot][wv2] = m; red[1][slot][wv2] = ss; }
        }
        __syncthreads();
        if (c < CC) {
            const float M = fmaxf(red[0][slot][0], red[0][slot][1]);
            e = __expf(x0 - M);
            q = e * x1;
            #pragma unroll
            for (int off = 1; off <= 32; off <<= 1) {
                const float te = __shfl_up(e, off);
                const float tq = __shfl_up(q, off);
                if (lane >= off) { e += te; q += tq; }
            }
            if (lane == 63) { red[2][slot][wv2] = e; red[3][slot][wv2] = q; }
        }
        __syncthreads();
        if (c < CC) {
            if (wv2 == 1) { e += red[2][slot][0]; q += red[3][slot][0]; }
            E [k*CC + c] = e;
            Qe[k*CC + c] = q;
            if (k == 0) mnL[c] = (red[1][slot][0] + red[1][slot][1]) * (1.f/SS);
        }
        __syncthreads();
    }

    const float* __restrict__ st1 = s1w + (size_t)(R_TOT + b*SS)*CC;  // [j][c]
    float* __restrict__ o = out + (size_t)bi*SS*CC;
    if (tid < 448) {
        const int e0 = tid * 4;
        float v[4];
        #pragma unroll
        for (int u = 0; u < 4; ++u) {
            const int idx = e0 + u;
            const int j = idx / CC, c = idx - j*CC;
            float add;
            if (i <= j) {
                const float Ei = (i > 0) ? E [(i-1)*CC + c] : 0.f;
                const float Qi = (i > 0) ? Qe[(i-1)*CC + c] : 0.f;
                add = (Qe[j*CC + c] - Qi) / (E[j*CC + c] - Ei);
            } else {
                add = mnL[c];
            }
            v[u] = sh1L[c] + st1[idx] + uniL[c] + add;
        }
        *(float4*)&o[e0] = make_float4(v[0], v[1], v[2], v[3]);
    }
}

extern "C" void kernel_launch(void* const* d_in, const int* in_sizes, int n_in,
                              void* d_out, int out_size, void* d_ws, size_t ws_size,
                              hipStream_t stream)
{
    const float* mem = (const float*)d_in[0];
    AllP P;
    for (int n = 0; n < 3; ++n) {
        const int base = 1 + 8*n;
        P.n[n].W1  = (const float*)d_in[base+0];
        P.n[n].b1  = (const float*)d_in[base+1];
        P.n[n].W2  = (const float*)d_in[base+2];
        P.n[n].b2  = (const float*)d_in[base+3];
        P.n[n].s0W = (const float*)d_in[base+4];
        P.n[n].s0b = (const float*)d_in[base+5];
        P.n[n].s1W = (const float*)d_in[base+6];
        P.n[n].s1b = (const float*)d_in[base+7];
    }
    const float* uni = (const float*)d_in[25];
    float* ws  = (float*)d_ws;
    float* s0  = ws + S0_OFF;
    float* s1  = ws + S1_OFF;
    unsigned short* w1b = (unsigned short*)((char*)d_ws + W1B_OFF_BYTES);
    unsigned short* w2b = (unsigned short*)((char*)d_ws + W2B_OFF_BYTES);
    float* out = (float*)d_out;

    hipLaunchKernelGGL(cvt_kernel,   dim3(480),   dim3(512), 0, stream, P, w1b, w2b);
    hipLaunchKernelGGL(mlp_fused,    dim3(192),   dim3(512), 0, stream, mem, P, w1b, w2b, s0, s1);
    hipLaunchKernelGGL(final_kernel, dim3(BB*SS), dim3(512), 0, stream, s0, s1, uni, out);
}